// Round 3
// baseline (71.000 us; speedup 1.0000x reference)
//
#include <hip/hip_runtime.h>
#include <hip/hip_bf16.h>
#include <stdint.h>

// Chamfer distance, B=2, N=M=8192, fp32 3-D points — MFMA formulation.
//
// d2[n][m] = |p_n|^2 + |g_m|^2 - 2 p_n.g_m  computed ENTIRELY inside
// v_mfma_f32_32x32x16_bf16 via split-bf16 (hi+lo) encoding, K=16:
//   A_k (pred row): [-2hp,-2hp, -2lp,-2lp, h(p2), l(p2), 1, 1]   (3 coords each)
//   B_k (gt col)  : [ hg,  lg,   hg,  lg,  1,     1, h(g2), l(g2)]
//   sum = -2(hp+lp).(hg+lg) + p2 + g2 = d2  (split residual ~2^-18 rel)
// One matrix serves BOTH chamfer directions: row-mins (pred->gt) and
// col-mins (gt->pred) -> 134M pairs instead of 268M pair-dirs.
// Epilogue per 32x32 tile: min3-tree over 16 accs (col-min) + 16 min3
// rowmin folds. B-fragments read straight from L2 with a 4-tile prefetch ring.

typedef __attribute__((ext_vector_type(8))) short short8v;
typedef __attribute__((ext_vector_type(16))) float f32x16;

#define NP 8192
#define NSTRIPE 256        // NP/32 row stripes
#define NCHUNK 4           // col chunks
#define CHUNKCOLS 2048
#define NT 64              // col tiles per wave = CHUNKCOLS/32
#define SCALE 0.390625f    // 80^2 / (2 * 8192)

// ws byte offsets
#define OFF_COL 0u          // float[2][256][8192]  col-min partials (16 MB)
#define OFF_ROW 16777216u   // float[2][4][8192]    row-min partials (256 KB)
#define OFF_PA  17825792u   // ushort[2][8192][16]  packed pred (512 KB)
#define OFF_PB  18874368u   // ushort[2][8192][16]  packed gt   (512 KB)

__device__ inline uint32_t f2u(float f){ union{float f;uint32_t u;}c; c.f=f; return c.u; }
__device__ inline float u2f(uint32_t u){ union{float f;uint32_t u;}c; c.u=u; return c.f; }
__device__ inline uint16_t bfr(float f){ uint32_t u=f2u(f); return (uint16_t)((u + 0x7FFFu + ((u>>16)&1u))>>16); }
__device__ inline float bff(uint16_t s){ return u2f(((uint32_t)s)<<16); }
__device__ inline float min3f(float a,float b,float c){ return fminf(fminf(a,b),c); }

__global__ __launch_bounds__(256) void prep_kernel(
    const float* __restrict__ pred, const float* __restrict__ gt,
    float* __restrict__ out, uint8_t* __restrict__ ws) {
  const int tid = blockIdx.x*256 + (int)threadIdx.x;  // 0..16383
  if (tid == 0) out[0] = 0.0f;
  const int b = tid >> 13, i = tid & 8191;
  const float* p = pred + ((size_t)b*NP + i)*3;
  const float* g = gt   + ((size_t)b*NP + i)*3;
  ushort* PA = (ushort*)(ws + OFF_PA) + ((size_t)b*NP + i)*16;
  ushort* PB = (ushort*)(ws + OFF_PB) + ((size_t)b*NP + i)*16;

  {  // pred -> A-side
    const float x=p[0], y=p[1], z=p[2];
    const uint16_t hx=bfr(x), hy=bfr(y), hz=bfr(z);
    const uint16_t lx=bfr(x-bff(hx)), ly=bfr(y-bff(hy)), lz=bfr(z-bff(hz));
    const float p2 = fmaf(x,x,fmaf(y,y,z*z));
    const uint16_t h2=bfr(p2), l2=bfr(p2-bff(h2));
    union{ ushort u[16]; uint4 v[2]; } A;
    A.u[0]=bfr(-2.f*bff(hx)); A.u[1]=bfr(-2.f*bff(hy)); A.u[2]=bfr(-2.f*bff(hz));
    A.u[3]=A.u[0]; A.u[4]=A.u[1]; A.u[5]=A.u[2];
    A.u[6]=bfr(-2.f*bff(lx)); A.u[7]=bfr(-2.f*bff(ly)); A.u[8]=bfr(-2.f*bff(lz));
    A.u[9]=A.u[6]; A.u[10]=A.u[7]; A.u[11]=A.u[8];
    A.u[12]=h2; A.u[13]=l2; A.u[14]=0x3F80; A.u[15]=0x3F80;
    ((uint4*)PA)[0]=A.v[0]; ((uint4*)PA)[1]=A.v[1];
  }
  {  // gt -> B-side
    const float x=g[0], y=g[1], z=g[2];
    const uint16_t hx=bfr(x), hy=bfr(y), hz=bfr(z);
    const uint16_t lx=bfr(x-bff(hx)), ly=bfr(y-bff(hy)), lz=bfr(z-bff(hz));
    const float g2 = fmaf(x,x,fmaf(y,y,z*z));
    const uint16_t h2=bfr(g2), l2=bfr(g2-bff(h2));
    union{ ushort u[16]; uint4 v[2]; } B;
    B.u[0]=hx; B.u[1]=hy; B.u[2]=hz; B.u[3]=lx; B.u[4]=ly; B.u[5]=lz;
    B.u[6]=hx; B.u[7]=hy; B.u[8]=hz; B.u[9]=lx; B.u[10]=ly; B.u[11]=lz;
    B.u[12]=0x3F80; B.u[13]=0x3F80; B.u[14]=h2; B.u[15]=l2;
    ((uint4*)PB)[0]=B.v[0]; ((uint4*)PB)[1]=B.v[1];
  }
}

__global__ __launch_bounds__(256) void chamfer_mfma_kernel(uint8_t* __restrict__ ws) {
  const ushort* PA = (const ushort*)(ws + OFF_PA);
  const ushort* PB = (const ushort*)(ws + OFF_PB);
  float* WCOL = (float*)(ws + OFF_COL);
  float* WROW = (float*)(ws + OFF_ROW);

  const int wave = threadIdx.x >> 6, lane = threadIdx.x & 63;
  const int half = lane >> 5, l31 = lane & 31;
  const int stripe = blockIdx.x*4 + wave;   // 0..255
  const int chunk  = blockIdx.y;            // 0..3
  const int b      = blockIdx.z;            // 0..1

  // A fragment: row = stripe*32 + l31, k = half*8 + i
  const int arow = stripe*32 + l31;
  const short8v afrag = *(const short8v*)(PA + ((size_t)(b*NP + arow))*16 + half*8);

  const ushort* pb0 = PB + ((size_t)(b*NP + chunk*CHUNKCOLS + l31))*16 + half*8;
#define LDB(ct) (*(const short8v*)(pb0 + (size_t)(ct)*512))

  const f32x16 zero = {};
  float rowmin[16];
#pragma unroll
  for (int i=0;i<16;++i) rowmin[i] = 3.4e38f;

  short8v bA=LDB(0), bB=LDB(1), bC=LDB(2), bD=LDB(3);
#pragma unroll 2
  for (int tp=0; tp<NT/2; ++tp) {
    const int t0 = 2*tp;
    const short8v nA = LDB((t0+4)&(NT-1));   // wrap: harmless re-read at tail
    const short8v nB = LDB((t0+5)&(NT-1));
    const f32x16 aA = __builtin_amdgcn_mfma_f32_32x32x16_bf16(afrag, bA, zero, 0,0,0);
    const f32x16 aB = __builtin_amdgcn_mfma_f32_32x32x16_bf16(afrag, bB, zero, 0,0,0);

    // col-min: per-lane tree over 16 rows, then cross-half combine
    float cA, cB;
    {
      const float m0=min3f(aA[0],aA[1],aA[2]), m1=min3f(aA[3],aA[4],aA[5]);
      const float m2=min3f(aA[6],aA[7],aA[8]), m3=min3f(aA[9],aA[10],aA[11]);
      const float m4=min3f(aA[12],aA[13],aA[14]);
      cA = fminf(min3f(m0,m1,aA[15]), min3f(m2,m3,m4));
    }
    {
      const float m0=min3f(aB[0],aB[1],aB[2]), m1=min3f(aB[3],aB[4],aB[5]);
      const float m2=min3f(aB[6],aB[7],aB[8]), m3=min3f(aB[9],aB[10],aB[11]);
      const float m4=min3f(aB[12],aB[13],aB[14]);
      cB = fminf(min3f(m0,m1,aB[15]), min3f(m2,m3,m4));
    }
    cA = fminf(cA, __shfl_xor(cA, 32));
    cB = fminf(cB, __shfl_xor(cB, 32));
    if (half == 0) {
      const size_t base = (size_t)(b*NSTRIPE + stripe)*NP + chunk*CHUNKCOLS;
      WCOL[base + t0*32 + l31]     = cA;
      WCOL[base + (t0+1)*32 + l31] = cB;
    }
#pragma unroll
    for (int i=0;i<16;++i) rowmin[i] = min3f(rowmin[i], aA[i], aB[i]);
    bA=bC; bB=bD; bC=nA; bD=nB;
  }
#undef LDB

  // row-min: reduce across the 32 cols held by this half-wave
#pragma unroll
  for (int i=0;i<16;++i) {
    float v = rowmin[i];
    v = fminf(v, __shfl_xor(v, 1));
    v = fminf(v, __shfl_xor(v, 2));
    v = fminf(v, __shfl_xor(v, 4));
    v = fminf(v, __shfl_xor(v, 8));
    v = fminf(v, __shfl_xor(v, 16));
    rowmin[i] = v;
  }
  if (l31 == 0) {
    float* wr = WROW + (size_t)(b*NCHUNK + chunk)*NP + stripe*32 + half*4;
#pragma unroll
    for (int i=0;i<16;++i) wr[(i&3) + 8*(i>>2)] = rowmin[i];  // C/D row map (m74)
  }
}

__global__ __launch_bounds__(256) void reduce_kernel(
    const uint8_t* __restrict__ ws, float* __restrict__ out) {
  const float* WCOL = (const float*)(ws + OFF_COL);
  const float* WROW = (const float*)(ws + OFF_ROW);
  const int tid = blockIdx.x*256 + (int)threadIdx.x;  // 0..16383
  const int b = tid >> 13, q = tid & 8191;

  const float* pc = WCOL + (size_t)b*NSTRIPE*NP + q;
  float mn = 3.4e38f;
#pragma unroll 8
  for (int s=0; s<NSTRIPE; ++s) mn = fminf(mn, pc[(size_t)s*NP]);

  const float* pr = WROW + (size_t)b*NCHUNK*NP + q;
  const float mr = fminf(fminf(pr[0], pr[NP]), fminf(pr[2*NP], pr[3*NP]));

  float sum = fmaxf(mn, 0.0f) + fmaxf(mr, 0.0f);  // clamp == ref's maximum(d2,0)
#pragma unroll
  for (int off=32; off>0; off>>=1) sum += __shfl_down(sum, off);
  __shared__ float red[4];
  if ((threadIdx.x & 63) == 0) red[threadIdx.x >> 6] = sum;
  __syncthreads();
  if (threadIdx.x == 0) atomicAdd(out, (red[0]+red[1]+red[2]+red[3]) * SCALE);
}

extern "C" void kernel_launch(void* const* d_in, const int* in_sizes, int n_in,
                              void* d_out, int out_size, void* d_ws, size_t ws_size,
                              hipStream_t stream) {
  const float* pred = (const float*)d_in[0];
  const float* gt = (const float*)d_in[1];
  float* out = (float*)d_out;
  uint8_t* ws = (uint8_t*)d_ws;

  prep_kernel<<<64, 256, 0, stream>>>(pred, gt, out, ws);
  chamfer_mfma_kernel<<<dim3(64, NCHUNK, 2), 256, 0, stream>>>(ws);
  reduce_kernel<<<64, 256, 0, stream>>>(ws, out);
}

// Round 4
// 30.480 us; speedup vs baseline: 2.3294x; 2.3294x over previous
//
#include <hip/hip_runtime.h>
#include <hip/hip_bf16.h>
#include <stdint.h>

// Chamfer distance, B=2, N=M=8192, fp32 3-D points — MFMA, two transposed passes.
//
// d2[n][m] = |p_n|^2 + |g_m|^2 - 2 p_n.g_m inside v_mfma_f32_32x32x16_bf16 via
// split-bf16 (hi+lo), K=16 (encoding verified R3: absmax 0.0):
//   A_k: [-2hx,-2hy,-2hz, -2hx,-2hy,-2hz, -2lx,-2ly,-2lz, -2lx,-2ly,-2lz, h2,l2,1,1]
//   B_k: [ hx, hy, hz,  lx, ly, lz,  hx, hy, hz,  lx, ly, lz,  1,1, h2,l2]
// R4 vs R3 (71us): drop the one-pass col-min path (per-tile min-tree + shfl +
// 16MB WCOL partials + latency-bound reduce). Instead run TWO passes with A/B
// swapped; each pass needs only row-mins, folded in-register (16 v_min3 per 2
// MFMAs — whole epilogue). WROW partials = 512KB (L2-hot), reduce = 4 loads/thr.

typedef __attribute__((ext_vector_type(8))) short short8v;
typedef __attribute__((ext_vector_type(16))) float f32x16;

#define NP 8192
#define NCHUNK 4
#define CHUNKCOLS 2048
#define NT 64              // 32-col tiles per chunk
#define SCALE 0.390625f    // 80^2 / (2 * 8192)

// ws byte offsets
#define OFF_ROW 0u          // float[4(db)][4(chunk)][8192]   row-min partials (512 KB)
#define OFF_A   1048576u    // ushort[4(db)][8192][16]        A-encoded points (1 MB)
#define OFF_B   2097152u    // ushort[4(db)][8192][16]        B-encoded points (1 MB)
// db = dir*2 + b.  Pass dir0: A=pred[b], B=gt[b].  Pass dir1: A=gt[b], B=pred[b].

__device__ inline uint32_t f2u(float f){ union{float f;uint32_t u;}c; c.f=f; return c.u; }
__device__ inline float u2f(uint32_t u){ union{float f;uint32_t u;}c; c.u=u; return c.f; }
__device__ inline uint16_t bfr(float f){ uint32_t u=f2u(f); return (uint16_t)((u + 0x7FFFu + ((u>>16)&1u))>>16); }
__device__ inline float bff(uint16_t s){ return u2f(((uint32_t)s)<<16); }
__device__ inline float min3f(float a,float b,float c){ return fminf(fminf(a,b),c); }

__device__ inline void packA(float x, float y, float z, ushort* dst) {
  const uint16_t hx=bfr(x), hy=bfr(y), hz=bfr(z);
  const uint16_t lx=bfr(x-bff(hx)), ly=bfr(y-bff(hy)), lz=bfr(z-bff(hz));
  const float s2 = fmaf(x,x,fmaf(y,y,z*z));
  const uint16_t h2=bfr(s2), l2=bfr(s2-bff(h2));
  union{ ushort u[16]; uint4 v[2]; } A;
  A.u[0]=bfr(-2.f*bff(hx)); A.u[1]=bfr(-2.f*bff(hy)); A.u[2]=bfr(-2.f*bff(hz));
  A.u[3]=A.u[0]; A.u[4]=A.u[1]; A.u[5]=A.u[2];
  A.u[6]=bfr(-2.f*bff(lx)); A.u[7]=bfr(-2.f*bff(ly)); A.u[8]=bfr(-2.f*bff(lz));
  A.u[9]=A.u[6]; A.u[10]=A.u[7]; A.u[11]=A.u[8];
  A.u[12]=h2; A.u[13]=l2; A.u[14]=0x3F80; A.u[15]=0x3F80;
  ((uint4*)dst)[0]=A.v[0]; ((uint4*)dst)[1]=A.v[1];
}

__device__ inline void packB(float x, float y, float z, ushort* dst) {
  const uint16_t hx=bfr(x), hy=bfr(y), hz=bfr(z);
  const uint16_t lx=bfr(x-bff(hx)), ly=bfr(y-bff(hy)), lz=bfr(z-bff(hz));
  const float s2 = fmaf(x,x,fmaf(y,y,z*z));
  const uint16_t h2=bfr(s2), l2=bfr(s2-bff(h2));
  union{ ushort u[16]; uint4 v[2]; } B;
  B.u[0]=hx; B.u[1]=hy; B.u[2]=hz; B.u[3]=lx; B.u[4]=ly; B.u[5]=lz;
  B.u[6]=hx; B.u[7]=hy; B.u[8]=hz; B.u[9]=lx; B.u[10]=ly; B.u[11]=lz;
  B.u[12]=0x3F80; B.u[13]=0x3F80; B.u[14]=h2; B.u[15]=l2;
  ((uint4*)dst)[0]=B.v[0]; ((uint4*)dst)[1]=B.v[1];
}

__global__ __launch_bounds__(256) void prep_kernel(
    const float* __restrict__ pred, const float* __restrict__ gt,
    float* __restrict__ out, uint8_t* __restrict__ ws) {
  const int tid = blockIdx.x*256 + (int)threadIdx.x;  // 0..16383
  if (tid == 0) out[0] = 0.0f;
  const int b = tid >> 13, i = tid & 8191;
  const float* p = pred + ((size_t)b*NP + i)*3;
  const float* g = gt   + ((size_t)b*NP + i)*3;
  const float px=p[0], py=p[1], pz=p[2];
  const float gx=g[0], gy=g[1], gz=g[2];
  ushort* A = (ushort*)(ws + OFF_A);
  ushort* Bp = (ushort*)(ws + OFF_B);
  // db = dir*2 + b
  packA(px,py,pz, A  + ((size_t)(0*2+b)*NP + i)*16);  // dir0 A = pred
  packB(gx,gy,gz, Bp + ((size_t)(0*2+b)*NP + i)*16);  // dir0 B = gt
  packA(gx,gy,gz, A  + ((size_t)(1*2+b)*NP + i)*16);  // dir1 A = gt
  packB(px,py,pz, Bp + ((size_t)(1*2+b)*NP + i)*16);  // dir1 B = pred
}

__global__ __launch_bounds__(256) void chamfer_mfma_kernel(uint8_t* __restrict__ ws) {
  const int wave = threadIdx.x >> 6, lane = threadIdx.x & 63;
  const int half = lane >> 5, l31 = lane & 31;
  const int stripe = blockIdx.x*4 + wave;   // 0..255 (row stripe of 32)
  const int chunk  = blockIdx.y;            // 0..3
  const int db     = blockIdx.z;            // 0..3 = dir*2 + b

  const ushort* PA = (const ushort*)(ws + OFF_A) + (size_t)db*NP*16;
  const ushort* PB = (const ushort*)(ws + OFF_B) + (size_t)db*NP*16;
  float* WROW = (float*)(ws + OFF_ROW);

  const int arow = stripe*32 + l31;
  const short8v afrag = *(const short8v*)(PA + (size_t)arow*16 + half*8);

  const ushort* pb0 = PB + ((size_t)(chunk*CHUNKCOLS + l31))*16 + half*8;
#define LDB(ct) (*(const short8v*)(pb0 + (size_t)(ct)*512))

  const f32x16 zero = {};
  float rowmin[16];
#pragma unroll
  for (int i=0;i<16;++i) rowmin[i] = 3.4e38f;

  short8v bA=LDB(0), bB=LDB(1), bC=LDB(2), bD=LDB(3);
#pragma unroll 2
  for (int tp=0; tp<NT/2; ++tp) {
    const int t0 = 2*tp;
    const short8v nA = LDB((t0+4)&(NT-1));   // wrap: harmless re-read at tail
    const short8v nB = LDB((t0+5)&(NT-1));
    const f32x16 aA = __builtin_amdgcn_mfma_f32_32x32x16_bf16(afrag, bA, zero, 0,0,0);
    const f32x16 aB = __builtin_amdgcn_mfma_f32_32x32x16_bf16(afrag, bB, zero, 0,0,0);
#pragma unroll
    for (int i=0;i<16;++i) rowmin[i] = min3f(rowmin[i], aA[i], aB[i]);
    bA=bC; bB=bD; bC=nA; bD=nB;
  }
#undef LDB

  // row-min across the 32 cols held per half-wave, then lane 0 writes.
#pragma unroll
  for (int i=0;i<16;++i) {
    float v = rowmin[i];
    v = fminf(v, __shfl_xor(v, 1));
    v = fminf(v, __shfl_xor(v, 2));
    v = fminf(v, __shfl_xor(v, 4));
    v = fminf(v, __shfl_xor(v, 8));
    v = fminf(v, __shfl_xor(v, 16));
    rowmin[i] = v;
  }
  if (l31 == 0) {
    // C/D map (verified): row = (i&3) + 8*(i>>2) + 4*half
    float* wr = WROW + ((size_t)db*NCHUNK + chunk)*NP + stripe*32 + half*4;
#pragma unroll
    for (int i=0;i<16;++i) wr[(i&3) + 8*(i>>2)] = rowmin[i];
  }
}

__global__ __launch_bounds__(256) void reduce_kernel(
    const uint8_t* __restrict__ ws, float* __restrict__ out) {
  const float* WROW = (const float*)(ws + OFF_ROW);
  const int tid = blockIdx.x*256 + (int)threadIdx.x;  // 0..32767
  const int db = tid >> 13, q = tid & 8191;

  const float* pr = WROW + (size_t)db*NCHUNK*NP + q;
  const float m0 = fminf(pr[0], pr[NP]);
  const float m1 = fminf(pr[2*NP], pr[3*NP]);
  float sum = fmaxf(fminf(m0, m1), 0.0f);  // clamp == ref's maximum(d2,0)

#pragma unroll
  for (int off=32; off>0; off>>=1) sum += __shfl_down(sum, off);
  __shared__ float red[4];
  if ((threadIdx.x & 63) == 0) red[threadIdx.x >> 6] = sum;
  __syncthreads();
  if (threadIdx.x == 0) atomicAdd(out, (red[0]+red[1]+red[2]+red[3]) * SCALE);
}

extern "C" void kernel_launch(void* const* d_in, const int* in_sizes, int n_in,
                              void* d_out, int out_size, void* d_ws, size_t ws_size,
                              hipStream_t stream) {
  const float* pred = (const float*)d_in[0];
  const float* gt = (const float*)d_in[1];
  float* out = (float*)d_out;
  uint8_t* ws = (uint8_t*)d_ws;

  prep_kernel<<<64, 256, 0, stream>>>(pred, gt, out, ws);
  chamfer_mfma_kernel<<<dim3(64, NCHUNK, 4), 256, 0, stream>>>(ws);
  reduce_kernel<<<128, 256, 0, stream>>>(ws, out);
}